// Round 12
// baseline (268.996 us; speedup 1.0000x reference)
//
#include <hip/hip_runtime.h>

#define D_DIM 256
#define K_CODES 1024
#define T_DIM 4096
#define MTILE 128
#define NCHUNK 32                           // codes per chunk
#define NCHUNKS (K_CODES / NCHUNK)          // 32
#define HCHUNK_BYTES 16384                  // 16 ks x 1024 B hi-fragments per chunk
#define LO_BASE (NCHUNKS * HCHUNK_BYTES)    // 512 KiB: lo image follows hi image

typedef _Float16 f16x8 __attribute__((ext_vector_type(8)));
typedef float    f32x16 __attribute__((ext_vector_type(16)));

#define ZERO16 {0.f,0.f,0.f,0.f,0.f,0.f,0.f,0.f,0.f,0.f,0.f,0.f,0.f,0.f,0.f,0.f}

// ws layout: [0,4096): eN f32[1024]; [4096, 4096+1 MiB): B-fragment image,
// hi-part chunks [0,512K) then lo-part chunks [512K,1M).
// Fragment (c, ks) is 1024 B in exact mfma_f32_32x32x16_f16 B lane order:
// lane holds code = c*32+(lane&31), k = ks*16+(lane>>5)*8+j.
// hi is LDS-staged (feeds 2 of 3 passes); lo streams from L2 via a 4-deep
// register prefetch queue (feeds 1 pass) -> LDS-unit load halves, and the
// two memory pipes (LDS + vector-mem) run in parallel under the MFMA stream.

// --- prep 1: eN[k] = ||E[k]||^2 (fp64 accum) ---
__global__ __launch_bounds__(256) void vq_norm_kernel(const float* __restrict__ E,
                                                      float* __restrict__ eN) {
    __shared__ double wsum[4];
    const int k = blockIdx.x;
    const int tid = threadIdx.x;
    float v = E[(size_t)k * D_DIM + tid];
    double s = (double)v * (double)v;
    #pragma unroll
    for (int off = 32; off > 0; off >>= 1)
        s += __shfl_down(s, off);
    if ((tid & 63) == 0) wsum[tid >> 6] = s;
    __syncthreads();
    if (tid == 0) eN[k] = (float)((wsum[0] + wsum[1]) + (wsum[2] + wsum[3]));
}

// --- prep 2: E -> f16 hi/lo 32x32x16 B-fragment images (hi block, lo block) ---
__global__ __launch_bounds__(256) void vq_prep_e(const float* __restrict__ E,
                                                 char* __restrict__ img) {
    const int g    = blockIdx.x * 256 + threadIdx.x;   // 0..32767
    const int c    = g >> 10;          // chunk 0..31
    const int ks   = (g >> 6) & 15;    // k-step 0..15
    const int lane = g & 63;
    const int code = c * NCHUNK + (lane & 31);
    const int k0   = ks * 16 + (lane >> 5) * 8;
    const float* src = E + (size_t)code * D_DIM + k0;
    f16x8 hi, lo;
    #pragma unroll
    for (int j = 0; j < 8; ++j) {
        float v = src[j];
        _Float16 h = (_Float16)v;
        hi[j] = h;
        lo[j] = (_Float16)(v - (float)h);
    }
    size_t off = (size_t)c * HCHUNK_BYTES + (size_t)ks * 1024 + lane * 16;
    *(f16x8*)(img + off)           = hi;
    *(f16x8*)(img + LO_BASE + off) = lo;
}

__device__ __forceinline__ void stage_chunk(const char* gsrc, char* ldsdst, int tid) {
    const int lane = tid & 63;
    const int woff = (tid >> 6) << 10;   // wave*1024
    #pragma unroll
    for (int r = 0; r < 4; ++r) {        // 16 KB: 4 rounds x 256 threads x 16 B
        __builtin_amdgcn_global_load_lds(
            (const __attribute__((address_space(1))) void*)(gsrc + r * 4096 + woff + (size_t)lane * 16),
            (__attribute__((address_space(3))) void*)(ldsdst + r * 4096 + woff),
            16, 0, 0);
    }
}

__global__ __launch_bounds__(256, 2) void vq_mfma_kernel(const float* __restrict__ z,
                                                         const float* __restrict__ E,
                                                         const float* __restrict__ eN_g,
                                                         const char* __restrict__ imgE,
                                                         float* __restrict__ out) {
    __shared__ __align__(16) char lds_all[2 * HCHUNK_BYTES + 4096 + 512];
    char*  lds_e = lds_all;
    float* eN_s  = (float*)(lds_all + 2 * HCHUNK_BYTES);
    int*   idx_s = (int*)(lds_all + 2 * HCHUNK_BYTES + 4096);

    const int tid  = threadIdx.x;
    const int lane = tid & 63;
    const int w    = tid >> 6;        // wave 0..3
    const int l31  = lane & 31;
    const int khal = lane >> 5;       // k-group half 0..1
    const int bb   = blockIdx.y;
    const int t0b  = blockIdx.x * MTILE;

    // ---- A fragments for 32x32x16: wave w owns points t0b + w*32 .. +31.
    // Lane holds row = lane&31, k = ks*16 + (lane>>5)*8 + j. ~128 regs on the
    // AGPR side -> reg-capped at 2 waves/SIMD (round-6 spill proof); budget
    // A 128 + acc 48 + blq 16 + misc ~ 220 <= 256.
    const float* zb = z + (size_t)bb * D_DIM * T_DIM + t0b;
    const int tcol = w * 32 + l31;
    f16x8 a_hi[16], a_lo[16];
    #pragma unroll
    for (int ks = 0; ks < 16; ++ks) {
        #pragma unroll
        for (int j = 0; j < 8; ++j) {
            float v = zb[(size_t)(ks * 16 + khal * 8 + j) * T_DIM + tcol];
            _Float16 h = (_Float16)v;
            a_hi[ks][j] = h;
            a_lo[ks][j] = (_Float16)(v - (float)h);
        }
    }

    // ---- stage eN + first hi-chunk
    for (int i = tid; i < K_CODES; i += 256) eN_s[i] = eN_g[i];
    stage_chunk(imgE, lds_e, tid);
    __syncthreads();

    float best[16];
    int   bestk[16];
    #pragma unroll
    for (int r = 0; r < 16; ++r) { best[r] = __builtin_huge_valf(); bestk[r] = 0; }

    for (int c = 0; c < NCHUNKS; ++c) {
        const char* ebuf = lds_e + (c & 1) * HCHUNK_BYTES;
        if (c + 1 < NCHUNKS)
            stage_chunk(imgE + (size_t)(c + 1) * HCHUNK_BYTES,
                        lds_e + ((c + 1) & 1) * HCHUNK_BYTES, tid);

        // per-lane code norm for this chunk (same for all 16 acc rows)
        const int   n  = c * NCHUNK + l31;
        const float en = eN_s[n];

        // lo-part stream base for this chunk (L2-resident, coalesced 1KB/load)
        const char* glo = imgE + LO_BASE + (size_t)c * HCHUNK_BYTES + lane * 16;

        // 4-deep register prefetch queue for bl: load->use distance = 12 MFMAs
        // (~300+ cyc) hides L1/L2 latency that killed the round-8 pure-stream.
        f16x8 blq[4];
        #pragma unroll
        for (int p = 0; p < 4; ++p)
            blq[p] = *(const f16x8*)(glo + p * 1024);

        // 3 independent accumulator chains (one per pass)
        f32x16 aH = ZERO16, aM = ZERO16, aL = ZERO16;

        #pragma unroll
        for (int ks = 0; ks < 16; ++ks) {
            f16x8 bh = *(const f16x8*)(ebuf + ks * 1024 + lane * 16);  // 1KB wave read
            aH = __builtin_amdgcn_mfma_f32_32x32x16_f16(a_hi[ks], bh, aH, 0, 0, 0);
            aM = __builtin_amdgcn_mfma_f32_32x32x16_f16(a_lo[ks], bh, aM, 0, 0, 0);
            f16x8 blcur = blq[ks & 3];              // static index (full unroll)
            if (ks + 4 < 16)
                blq[ks & 3] = *(const f16x8*)(glo + (ks + 4) * 1024);
            aL = __builtin_amdgcn_mfma_f32_32x32x16_f16(a_hi[ks], blcur, aL, 0, 0, 0);
        }

        #pragma unroll
        for (int r = 0; r < 16; ++r) {
            float dist = fmaf(-2.0f, (aH[r] + aM[r]) + aL[r], en);
            // strict < with ascending n == first-min tie-break (matches jnp.argmin)
            if (dist < best[r]) { best[r] = dist; bestk[r] = n; }
        }

        __syncthreads();   // all waves done reading ebuf before it is restaged
    }

    // ---- cross-lane argmin over the 32 code-columns (within each 32-lane half)
    #pragma unroll
    for (int off = 1; off < 32; off <<= 1) {
        #pragma unroll
        for (int r = 0; r < 16; ++r) {
            float od = __shfl_xor(best[r], off, 64);
            int   ok = __shfl_xor(bestk[r], off, 64);
            if (od < best[r] || (od == best[r] && ok < bestk[r])) {
                best[r] = od; bestk[r] = ok;
            }
        }
    }
    if (l31 == 0) {
        #pragma unroll
        for (int r = 0; r < 16; ++r) {
            const int row = (r & 3) + 8 * (r >> 2) + 4 * khal;   // verified C/D map
            idx_s[w * 32 + row] = bestk[r];
        }
    }
    __syncthreads();

    // ---- fused gather: out[b][d][t0b+p] = E[idx[p]][d]
    const int p  = tid & 127;
    const int dh = tid >> 7;
    const int kk = idx_s[p];
    const float* er = E + (size_t)kk * D_DIM + dh * 128;
    float* ob = out + (size_t)bb * D_DIM * T_DIM + t0b + p;
    #pragma unroll 8
    for (int i = 0; i < 128; ++i)
        ob[(size_t)(dh * 128 + i) * T_DIM] = er[i];
}

extern "C" void kernel_launch(void* const* d_in, const int* in_sizes, int n_in,
                              void* d_out, int out_size, void* d_ws, size_t ws_size,
                              hipStream_t stream) {
    const float* z = (const float*)d_in[0];
    const float* E = (const float*)d_in[1];
    float* out = (float*)d_out;
    float* eN  = (float*)d_ws;
    char*  img = (char*)d_ws + 4096;

    const int B = in_sizes[0] / (D_DIM * T_DIM);   // 32

    vq_norm_kernel<<<dim3(K_CODES), dim3(256), 0, stream>>>(E, eN);
    vq_prep_e<<<dim3(128), dim3(256), 0, stream>>>(E, img);

    dim3 grid(T_DIM / MTILE, B);
    vq_mfma_kernel<<<grid, dim3(256), 0, stream>>>(z, E, eN, img, out);
}

// Round 13
// 224.868 us; speedup vs baseline: 1.1962x; 1.1962x over previous
//
#include <hip/hip_runtime.h>

#define D_DIM 256
#define K_CODES 1024
#define T_DIM 4096
#define MTILE 256                           // points per block (8 waves x 32)
#define NCHUNK 32                           // codes per chunk
#define NCHUNKS (K_CODES / NCHUNK)          // 32
#define CHUNK_BYTES 32768                   // 16 ks x 2 parts x 1024 B fragments

typedef _Float16 f16x8 __attribute__((ext_vector_type(8)));
typedef float    f32x16 __attribute__((ext_vector_type(16)));

#define ZERO16 {0.f,0.f,0.f,0.f,0.f,0.f,0.f,0.f,0.f,0.f,0.f,0.f,0.f,0.f,0.f,0.f}

// ws layout: [0,4096): eN f32[1024]; [4096, 4096+1 MiB): B-fragment image.
// Fragment (c, ks, part) is 1024 B in exact mfma_f32_32x32x16_f16 B lane
// order: lane holds code = c*32+(lane&31), k = ks*16+(lane>>5)*8+j.
// Linear staging, contiguous 1 KB wave reads -> zero bank conflicts (r9 PMC).

// --- prep 1: eN[k] = ||E[k]||^2 (fp64 accum) ---
__global__ __launch_bounds__(256) void vq_norm_kernel(const float* __restrict__ E,
                                                      float* __restrict__ eN) {
    __shared__ double wsum[4];
    const int k = blockIdx.x;
    const int tid = threadIdx.x;
    float v = E[(size_t)k * D_DIM + tid];
    double s = (double)v * (double)v;
    #pragma unroll
    for (int off = 32; off > 0; off >>= 1)
        s += __shfl_down(s, off);
    if ((tid & 63) == 0) wsum[tid >> 6] = s;
    __syncthreads();
    if (tid == 0) eN[k] = (float)((wsum[0] + wsum[1]) + (wsum[2] + wsum[3]));
}

// --- prep 2: E -> f16 hi/lo 32x32x16 B-fragment image ---
__global__ __launch_bounds__(256) void vq_prep_e(const float* __restrict__ E,
                                                 char* __restrict__ img) {
    const int g    = blockIdx.x * 256 + threadIdx.x;   // 0..32767
    const int c    = g >> 10;          // chunk 0..31
    const int ks   = (g >> 6) & 15;    // k-step 0..15
    const int lane = g & 63;
    const int code = c * NCHUNK + (lane & 31);
    const int k0   = ks * 16 + (lane >> 5) * 8;
    const float* src = E + (size_t)code * D_DIM + k0;
    f16x8 hi, lo;
    #pragma unroll
    for (int j = 0; j < 8; ++j) {
        float v = src[j];
        _Float16 h = (_Float16)v;
        hi[j] = h;
        lo[j] = (_Float16)(v - (float)h);
    }
    size_t off = (size_t)c * CHUNK_BYTES + (size_t)(ks * 2) * 1024 + lane * 16;
    *(f16x8*)(img + off)        = hi;
    *(f16x8*)(img + off + 1024) = lo;
}

// one quarter (8 KB) of a chunk: one global_load_lds per thread (512 threads)
__device__ __forceinline__ void stage_quarter(const char* gsrc, char* ldsdst,
                                              int q, int tid) {
    __builtin_amdgcn_global_load_lds(
        (const __attribute__((address_space(1))) void*)(gsrc + q * 8192 + (size_t)tid * 16),
        (__attribute__((address_space(3))) void*)(ldsdst + q * 8192 + ((tid >> 6) << 10)),
        16, 0, 0);
}

// 8-phase barrier-forced interleave (m201 template): per phase, ds_reads are
// issued before the first barrier, MFMAs run after lgkmcnt, closing barrier
// releases the next phase. Wave skew + LDS queue depth overlap the LDS unit
// with the matrix pipes BY CONSTRUCTION instead of relying on the scheduler.
__global__ __launch_bounds__(512, 2) void vq_mfma_kernel(const float* __restrict__ z,
                                                         const float* __restrict__ E,
                                                         const float* __restrict__ eN_g,
                                                         const char* __restrict__ imgE,
                                                         float* __restrict__ out) {
    __shared__ __align__(16) char lds_all[2 * CHUNK_BYTES + 4096 + 1024];
    char*  lds_e = lds_all;
    float* eN_s  = (float*)(lds_all + 2 * CHUNK_BYTES);
    int*   idx_s = (int*)(lds_all + 2 * CHUNK_BYTES + 4096);

    const int tid  = threadIdx.x;
    const int lane = tid & 63;
    const int w    = tid >> 6;        // wave 0..7
    const int l31  = lane & 31;
    const int khal = lane >> 5;       // k-group half 0..1
    const int bb   = blockIdx.y;
    const int t0b  = blockIdx.x * MTILE;

    // ---- A fragments for 32x32x16: wave w owns points t0b + w*32 .. +31.
    // ~128 regs; one chained acc keeps total ~217 < 256 (mandatory cap for
    // 512-thread blocks; round-6 proved spilling here is catastrophic).
    const float* zb = z + (size_t)bb * D_DIM * T_DIM + t0b;
    const int tcol = w * 32 + l31;
    f16x8 a_hi[16], a_lo[16];
    #pragma unroll
    for (int ks = 0; ks < 16; ++ks) {
        #pragma unroll
        for (int j = 0; j < 8; ++j) {
            float v = zb[(size_t)(ks * 16 + khal * 8 + j) * T_DIM + tcol];
            _Float16 h = (_Float16)v;
            a_hi[ks][j] = h;
            a_lo[ks][j] = (_Float16)(v - (float)h);
        }
    }

    // ---- stage eN + all of chunk 0
    for (int i = tid; i < K_CODES; i += 512) eN_s[i] = eN_g[i];
    #pragma unroll
    for (int q = 0; q < 4; ++q) stage_quarter(imgE, lds_e, q, tid);
    __syncthreads();   // prologue full drain: chunk 0 + eN visible

    float best[16];
    int   bestk[16];
    #pragma unroll
    for (int r = 0; r < 16; ++r) { best[r] = __builtin_huge_valf(); bestk[r] = 0; }

    f32x16 acc = ZERO16;

    for (int c = 0; c < NCHUNKS; ++c) {
        const char* ebuf = lds_e + (c & 1) * CHUNK_BYTES;
        const char* nsrc = imgE + (size_t)(c + 1) * CHUNK_BYTES;
        char*       nbuf = lds_e + ((c + 1) & 1) * CHUNK_BYTES;
        const int   n  = c * NCHUNK + l31;
        const float en = eN_s[n];
        const int   do_stage = (c + 1 < NCHUNKS);

        #pragma unroll
        for (int p = 0; p < 8; ++p) {
            const int ks0 = 2 * p;
            // phase reads (issued, not waited)
            f16x8 bh0 = *(const f16x8*)(ebuf + (size_t)(ks0 * 2 + 0) * 1024 + lane * 16);
            f16x8 bl0 = *(const f16x8*)(ebuf + (size_t)(ks0 * 2 + 1) * 1024 + lane * 16);
            f16x8 bh1 = *(const f16x8*)(ebuf + (size_t)(ks0 * 2 + 2) * 1024 + lane * 16);
            f16x8 bl1 = *(const f16x8*)(ebuf + (size_t)(ks0 * 2 + 3) * 1024 + lane * 16);
            if (p < 4 && do_stage) stage_quarter(nsrc, nbuf, p, tid);

            __builtin_amdgcn_s_barrier();
            asm volatile("s_waitcnt lgkmcnt(0)" ::: "memory");
            __builtin_amdgcn_sched_barrier(0);   // rule #18: pin MFMA after the wait
            __builtin_amdgcn_s_setprio(1);
            acc = __builtin_amdgcn_mfma_f32_32x32x16_f16(a_hi[ks0], bh0, acc, 0, 0, 0);
            acc = __builtin_amdgcn_mfma_f32_32x32x16_f16(a_lo[ks0], bh0, acc, 0, 0, 0);
            acc = __builtin_amdgcn_mfma_f32_32x32x16_f16(a_hi[ks0], bl0, acc, 0, 0, 0);
            acc = __builtin_amdgcn_mfma_f32_32x32x16_f16(a_hi[ks0 + 1], bh1, acc, 0, 0, 0);
            acc = __builtin_amdgcn_mfma_f32_32x32x16_f16(a_lo[ks0 + 1], bh1, acc, 0, 0, 0);
            acc = __builtin_amdgcn_mfma_f32_32x32x16_f16(a_hi[ks0 + 1], bl1, acc, 0, 0, 0);
            __builtin_amdgcn_s_setprio(0);
            __builtin_amdgcn_sched_barrier(0);
            if (p == 7)   // next chunk's buffer must be complete before its reads
                asm volatile("s_waitcnt vmcnt(0)" ::: "memory");
            __builtin_amdgcn_s_barrier();
        }

        // per-chunk epilogue (register-only)
        #pragma unroll
        for (int r = 0; r < 16; ++r) {
            float dist = fmaf(-2.0f, acc[r], en);
            // strict < with ascending n == first-min tie-break (matches jnp.argmin)
            if (dist < best[r]) { best[r] = dist; bestk[r] = n; }
        }
        acc = (f32x16)ZERO16;
    }

    // ---- cross-lane argmin over the 32 code-columns (within each 32-lane half)
    #pragma unroll
    for (int off = 1; off < 32; off <<= 1) {
        #pragma unroll
        for (int r = 0; r < 16; ++r) {
            float od = __shfl_xor(best[r], off, 64);
            int   ok = __shfl_xor(bestk[r], off, 64);
            if (od < best[r] || (od == best[r] && ok < bestk[r])) {
                best[r] = od; bestk[r] = ok;
            }
        }
    }
    if (l31 == 0) {
        #pragma unroll
        for (int r = 0; r < 16; ++r) {
            const int row = (r & 3) + 8 * (r >> 2) + 4 * khal;   // verified C/D map
            idx_s[w * 32 + row] = bestk[r];
        }
    }
    __syncthreads();

    // ---- fused gather: out[b][d][t0b+p] = E[idx[p]][d]
    const int p2 = tid & 255;
    const int dh = tid >> 8;
    const int kk = idx_s[p2];
    const float* er = E + (size_t)kk * D_DIM + dh * 128;
    float* ob = out + (size_t)bb * D_DIM * T_DIM + t0b + p2;
    #pragma unroll 8
    for (int i = 0; i < 128; ++i)
        ob[(size_t)(dh * 128 + i) * T_DIM] = er[i];
}

extern "C" void kernel_launch(void* const* d_in, const int* in_sizes, int n_in,
                              void* d_out, int out_size, void* d_ws, size_t ws_size,
                              hipStream_t stream) {
    const float* z = (const float*)d_in[0];
    const float* E = (const float*)d_in[1];
    float* out = (float*)d_out;
    float* eN  = (float*)d_ws;
    char*  img = (char*)d_ws + 4096;

    const int B = in_sizes[0] / (D_DIM * T_DIM);   // 32

    vq_norm_kernel<<<dim3(K_CODES), dim3(256), 0, stream>>>(E, eN);
    vq_prep_e<<<dim3(128), dim3(256), 0, stream>>>(E, img);

    dim3 grid(T_DIM / MTILE, B);
    vq_mfma_kernel<<<grid, dim3(512), 0, stream>>>(z, E, eN, img, out);
}